// Round 4
// baseline (264.888 us; speedup 1.0000x reference)
//
#include <hip/hip_runtime.h>
#include <hip/hip_bf16.h>
#include <math.h>

#define GG 8192      // graphs = B*T
#define NODESN 23
#define KK 8
#define DIN 16
#define HH 128
#define RHH 128
#define EPG (NODESN*KK)   // 184 edges per graph
#define TTT 128
#define BBB 64
#define HPAD 132     // h_hist row stride: 16B-aligned

// barrier with LDS-only drain: leaves global prefetch loads in flight
#define GRU_BARRIER() asm volatile("s_waitcnt lgkmcnt(0)\n\ts_barrier" ::: "memory")

// ---------------------------------------------------------------------------
// Kernel 1: per-graph GCN up to hsum (layer-1 + neighborhood aggregation).
// deg == 9 for every node, norm = 1/9. W1 column held in 16 VGPRs per thread.
// hsum[g] = sum over 9 slots (runner + its 8 srcs) of relu'd layer-1 rows.
// The layer-2 matmul (W2) is deferred to seq_kernel (batched GEMM).
// ---------------------------------------------------------------------------
__global__ __launch_bounds__(256) void gcn_hsum(
    const float* __restrict__ x, const int* __restrict__ esrc,
    const int* __restrict__ runner,
    const float* __restrict__ W1, const float* __restrict__ b1,
    float* __restrict__ hsum_g)
{
    __shared__ float xs[NODESN * DIN];    // 368 floats
    __shared__ int   srcs[EPG];           // 184
    __shared__ float t1[NODESN * HH];     // 2944 floats
    __shared__ float red[256];

    const int g   = blockIdx.x;
    const int tid = threadIdx.x;
    const int j   = tid & 127;
    const int nh  = tid >> 7;

    for (int i = tid; i < NODESN * DIN; i += 256) xs[i] = x[g * NODESN * DIN + i];
    for (int i = tid; i < EPG; i += 256)          srcs[i] = esrc[g * EPG + i] - g * NODESN;

    float w[DIN];
    #pragma unroll
    for (int k = 0; k < DIN; k++) w[k] = W1[k * HH + j];   // coalesced, L2-hot
    const float b1j = b1[j];
    __syncthreads();

    // t1 = x @ W1 : thread (j, nh) computes rows [nh*12, ...)
    const int n0 = nh * 12;
    const int n1 = nh ? NODESN : 12;
    for (int n = n0; n < n1; n++) {
        float acc = 0.f;
        #pragma unroll
        for (int k = 0; k < DIN; k += 4) {
            float4 xv = *(const float4*)&xs[n * DIN + k];   // broadcast
            acc = fmaf(xv.x, w[k], fmaf(xv.y, w[k+1], fmaf(xv.z, w[k+2], fmaf(xv.w, w[k+3], acc))));
        }
        t1[n * HH + j] = acc;
    }
    __syncthreads();

    const int r = runner[g];
    float part = 0.f;
    for (int slot = nh; slot < 9; slot += 2) {
        int node = (slot < 8) ? srcs[r * KK + slot] : r;
        float acc = t1[node * HH + j];
        #pragma unroll
        for (int k = 0; k < KK; k++) acc += t1[srcs[node * KK + k] * HH + j];
        part += fmaxf(acc * (1.f / 9.f) + b1j, 0.f);
    }
    red[tid] = part;
    __syncthreads();
    if (tid < HH) hsum_g[(size_t)g * HH + tid] = red[tid] + red[tid + 128];
}

// ---------------------------------------------------------------------------
// Kernel 2: seq = relu((1/9) * hsum @ W2 + b2) as a batched GEMM.
// 16 graphs per block; W2 columns streamed once per 16 rows (was: per graph).
// ---------------------------------------------------------------------------
__global__ __launch_bounds__(256) void seq_kernel(
    const float* __restrict__ hsum_g, const float* __restrict__ W2,
    const float* __restrict__ b2, float* __restrict__ seq)
{
    __shared__ float hs[16 * HH];         // 8 KB
    const int tid = threadIdx.x;
    const int j = tid & 127, mh = tid >> 7;
    const size_t base = (size_t)blockIdx.x * 16 * HH;

    for (int v = tid; v < 16 * HH / 4; v += 256)
        ((float4*)hs)[v] = ((const float4*)(hsum_g + base))[v];
    __syncthreads();

    float acc[8];
    #pragma unroll
    for (int m = 0; m < 8; m++) acc[m] = 0.f;
    const float* hrow = hs + mh * 8 * HH;
    for (int k = 0; k < HH; k += 4) {
        float w0  = W2[(k+0)*HH + j];
        float w1  = W2[(k+1)*HH + j];
        float w2v = W2[(k+2)*HH + j];
        float w3  = W2[(k+3)*HH + j];
        #pragma unroll
        for (int m = 0; m < 8; m++) {
            float4 hv = *(const float4*)&hrow[m * HH + k];  // wave-uniform broadcast
            acc[m] = fmaf(hv.x, w0, fmaf(hv.y, w1, fmaf(hv.z, w2v, fmaf(hv.w, w3, acc[m]))));
        }
    }
    const float bj = b2[j];
    #pragma unroll
    for (int m = 0; m < 8; m++)
        seq[base + (size_t)(mh * 8 + m) * HH + j] = fmaxf(acc[m] * (1.f/9.f) + bj, 0.f);
}

// ---------------------------------------------------------------------------
// Kernel 3: transpose W_ih [384,128] -> WT [128,384]
// ---------------------------------------------------------------------------
__global__ void transpose_wih(const float* __restrict__ W, float* __restrict__ WT)
{
    int idx = blockIdx.x * 256 + threadIdx.x;
    if (idx < 3 * RHH * RHH) {
        int jj = idx / RHH, kk = idx - jj * RHH;
        WT[kk * (3 * RHH) + jj] = W[idx];
    }
}

// ---------------------------------------------------------------------------
// Kernel 4: xg = seq @ W_ih^T + b_ih   [8192,128]@[128,384]
// ---------------------------------------------------------------------------
__global__ __launch_bounds__(384) void xg_kernel(
    const float* __restrict__ seq, const float* __restrict__ WT,
    const float* __restrict__ b_ih, float* __restrict__ xg)
{
    const int tid = threadIdx.x;
    const int m0 = blockIdx.x * 8;
    const float* srow = seq + (size_t)m0 * RHH;
    float acc[8];
    const float bv = b_ih[tid];
    #pragma unroll
    for (int mi = 0; mi < 8; mi++) acc[mi] = bv;
    for (int k = 0; k < RHH; k += 4) {
        float w0 = WT[(k+0)*384 + tid];
        float w1 = WT[(k+1)*384 + tid];
        float w2 = WT[(k+2)*384 + tid];
        float w3 = WT[(k+3)*384 + tid];
        #pragma unroll
        for (int mi = 0; mi < 8; mi++) {
            float4 sv = *(const float4*)(srow + mi * RHH + k);
            acc[mi] = fmaf(sv.x, w0, fmaf(sv.y, w1, fmaf(sv.z, w2, fmaf(sv.w, w3, acc[mi]))));
        }
    }
    #pragma unroll
    for (int mi = 0; mi < 8; mi++)
        xg[(size_t)(m0 + mi) * 384 + tid] = acc[mi];
}

// ---------------------------------------------------------------------------
// Kernel 5: GRU + fused output projection. 1024 threads per batch element.
// Thread (i,q): i = hidden unit (0..127), q = k-eighth (0..7) -> only 48
// W_hh floats/thread, pinned into VGPRs via empty asm (defeats remat/spill
// that plagued the 96-float/512-thread version: VGPR_Count was 80 < 96).
// Phase rotation (q>>1) spreads the 8 q-slices across all 32 banks.
// One LDS-only barrier per step.
// ---------------------------------------------------------------------------
__global__ __launch_bounds__(1024, 4) void gru_kernel(
    const float* __restrict__ xg, const float* __restrict__ W_hh,
    const float* __restrict__ b_hh, const float* __restrict__ Wp,
    const float* __restrict__ bp, float* __restrict__ out)
{
    __shared__ float h_hist[(TTT + 1) * HPAD];   // 68112 B
    __shared__ float xg_s[2][3 * RHH];           // 3072 B

    const int b   = blockIdx.x;
    const int tid = threadIdx.x;
    const int i   = tid >> 3;      // hidden index 0..127
    const int q   = tid & 7;       // k-eighth 0..7

    float wr[16], wz[16], wn[16];
    int loff[4];
    {
        const float* br = W_hh + (size_t)i * RHH;
        const float* bz = br + (size_t)RHH * RHH;
        const float* bn = bz + (size_t)RHH * RHH;
        #pragma unroll
        for (int m = 0; m < 4; m++) {
            int p = (m + (q >> 1)) & 3;
            int o = q * 16 + 4 * p;
            loff[m] = o;
            float4 v;
            v = *(const float4*)(br + o); wr[4*m]=v.x; wr[4*m+1]=v.y; wr[4*m+2]=v.z; wr[4*m+3]=v.w;
            v = *(const float4*)(bz + o); wz[4*m]=v.x; wz[4*m+1]=v.y; wz[4*m+2]=v.z; wz[4*m+3]=v.w;
            v = *(const float4*)(bn + o); wn[4*m]=v.x; wn[4*m+1]=v.y; wn[4*m+2]=v.z; wn[4*m+3]=v.w;
        }
    }
    // pin weights in VGPRs: value after asm is not a load result -> no remat
    #pragma unroll
    for (int m = 0; m < 16; m++) {
        asm volatile("" : "+v"(wr[m]));
        asm volatile("" : "+v"(wz[m]));
        asm volatile("" : "+v"(wn[m]));
    }

    float bhr = 0.f, bhz = 0.f, bhn = 0.f;
    if (q == 0) { bhr = b_hh[i]; bhz = b_hh[RHH + i]; bhn = b_hh[2 * RHH + i]; }

    if (tid < RHH) h_hist[tid] = 0.f;
    const float* xbase = xg + (size_t)b * TTT * 3 * RHH;
    float xnext = 0.f;
    if (tid < 3 * RHH) {
        xg_s[0][tid] = xbase[tid];             // t = 0
        xnext = xbase[3 * RHH + tid];          // t = 1
    }
    float hprev = 0.f;
    __syncthreads();

    for (int t = 0; t < TTT; t++) {
        const float* hrow = &h_hist[t * HPAD];
        float ar = 0.f, az = 0.f, an = 0.f;
        #pragma unroll
        for (int m = 0; m < 4; m++) {
            float4 hv = *(const float4*)(hrow + loff[m]);
            ar = fmaf(hv.x, wr[4*m], fmaf(hv.y, wr[4*m+1], fmaf(hv.z, wr[4*m+2], fmaf(hv.w, wr[4*m+3], ar))));
            az = fmaf(hv.x, wz[4*m], fmaf(hv.y, wz[4*m+1], fmaf(hv.z, wz[4*m+2], fmaf(hv.w, wz[4*m+3], az))));
            an = fmaf(hv.x, wn[4*m], fmaf(hv.y, wn[4*m+1], fmaf(hv.z, wn[4*m+2], fmaf(hv.w, wn[4*m+3], an))));
        }

        // publish next step's xg while dots are in flight
        if (tid < 3 * RHH) {
            xg_s[(t + 1) & 1][tid] = xnext;
            xnext = (t + 2 < TTT) ? xbase[(size_t)(t + 2) * 3 * RHH + tid] : 0.f;
        }

        // reduce across the 8 q-slices (low 3 lane bits)
        ar += __shfl_xor(ar, 1); ar += __shfl_xor(ar, 2); ar += __shfl_xor(ar, 4);
        az += __shfl_xor(az, 1); az += __shfl_xor(az, 2); az += __shfl_xor(az, 4);
        an += __shfl_xor(an, 1); an += __shfl_xor(an, 2); an += __shfl_xor(an, 4);

        if (q == 0) {
            const float* xr_s = xg_s[t & 1];
            float xr = xr_s[i], xz = xr_s[RHH + i], xn = xr_s[2 * RHH + i];
            float sr = xr + ar + bhr;
            float sz = xz + az + bhz;
            float rg = 1.f / (1.f + __expf(-sr));
            float zg = 1.f / (1.f + __expf(-sz));
            float tv = fmaf(rg, an + bhn, xn);
            tv = fminf(fmaxf(tv, -15.f), 15.f);
            float e2 = __expf(-2.f * tv);
            float ng = (1.f - e2) / (1.f + e2);
            hprev = fmaf(zg, hprev, (1.f - zg) * ng);
            h_hist[(t + 1) * HPAD + i] = hprev;
        }
        GRU_BARRIER();
    }

    // ---- stage Wp/bp, fused projection out[b,t,:] = h_hist[t+1] @ Wp + bp
    if (tid < 2 * RHH) xg_s[0][tid] = Wp[tid];
    if (tid < 2)       xg_s[1][tid] = bp[tid];
    __syncthreads();

    {
        const int s = tid & 3;            // k-quarter (shfl dist 1,2)
        const int c = (tid >> 2) & 1;     // output column
        const int t = tid >> 3;           // timestep 0..127
        float acc = 0.f;
        const float* hr = &h_hist[(t + 1) * HPAD + s * 32];
        #pragma unroll
        for (int ii = 0; ii < 32; ii += 4) {
            float4 hv = *(const float4*)(hr + ii);
            int k = s * 32 + ii;
            acc = fmaf(hv.x, xg_s[0][(k+0)*2 + c],
                  fmaf(hv.y, xg_s[0][(k+1)*2 + c],
                  fmaf(hv.z, xg_s[0][(k+2)*2 + c],
                  fmaf(hv.w, xg_s[0][(k+3)*2 + c], acc))));
        }
        acc += __shfl_xor(acc, 1);
        acc += __shfl_xor(acc, 2);
        if (s == 0)
            out[((size_t)b * TTT + t) * 2 + c] = acc + xg_s[1][c];
    }
}

extern "C" void kernel_launch(void* const* d_in, const int* in_sizes, int n_in,
                              void* d_out, int out_size, void* d_ws, size_t ws_size,
                              hipStream_t stream)
{
    const float* x      = (const float*)d_in[0];
    const int*   eidx   = (const int*)d_in[1];
    const int*   runner = (const int*)d_in[2];
    const float* W1     = (const float*)d_in[3];
    const float* b1     = (const float*)d_in[4];
    const float* W2     = (const float*)d_in[5];
    const float* b2     = (const float*)d_in[6];
    const float* W_ih   = (const float*)d_in[7];
    const float* W_hh   = (const float*)d_in[8];
    const float* b_ih   = (const float*)d_in[9];
    const float* b_hh   = (const float*)d_in[10];
    const float* Wp     = (const float*)d_in[11];
    const float* bp     = (const float*)d_in[12];
    float* out = (float*)d_out;

    float* seq    = (float*)d_ws;                    // [0, 4 MB)
    float* xg     = seq + (size_t)GG * HH;           // [4 MB, 16.6 MB)
    float* WT     = xg + (size_t)GG * 3 * RHH;       // [16.6, 16.8 MB)
    float* hsum_g = xg;  // alias: dead before xg_kernel writes xg

    transpose_wih<<<192, 256, 0, stream>>>(W_ih, WT);
    gcn_hsum<<<GG, 256, 0, stream>>>(x, eidx, runner, W1, b1, hsum_g);
    seq_kernel<<<GG / 16, 256, 0, stream>>>(hsum_g, W2, b2, seq);
    xg_kernel<<<GG / 8, 384, 0, stream>>>(seq, WT, b_ih, xg);
    gru_kernel<<<BBB, 1024, 0, stream>>>(xg, W_hh, b_hh, Wp, bp, out);
}